// Round 2
// baseline (678.488 us; speedup 1.0000x reference)
//
#include <hip/hip_runtime.h>
#include <math.h>
#include <stdint.h>

#define B_ 8
#define C_ 256
#define H_ 128
#define W_ 128
#define L_ 16384
#define LP_ 1024
#define NH_ 4

typedef __attribute__((ext_vector_type(8))) short bf16x8;
typedef __attribute__((ext_vector_type(4))) float f32x4;

__device__ __forceinline__ unsigned short f2bf(float f){
  unsigned int u = __float_as_uint(f);
  u += 0x7fffu + ((u >> 16) & 1u);
  return (unsigned short)(u >> 16);
}

// frag layout (gfx950 mfma_f32_16x16x32_bf16):
// A: row=lane&15, k=8*(lane>>4)+j ; B: col=lane&15, same k.
// LDS tiles are [row][K] k-major with 16B-slot XOR swizzle: phys = slot ^ (row&7).
__device__ __forceinline__ bf16x8 frag_ld(const unsigned short* tile, int row, int slot, int rowshorts){
  int phys = slot ^ (row & 7);
  union { uint4 u; bf16x8 h; } cv;
  cv.u = *(const uint4*)(tile + row * rowshorts + phys * 8);
  return cv.h;
}

// ---------------- K0: prep (weight casts + Vpw transpose + CPB bias table) ----------------
__global__ __launch_bounds__(256) void k0_prep(
    const float* __restrict__ scw, const float* __restrict__ pjw, const float* __restrict__ vpw,
    const float* __restrict__ w1, const float* __restrict__ b1, const float* __restrict__ w2,
    unsigned short* __restrict__ scw_bf, unsigned short* __restrict__ pjw_bf,
    unsigned short* __restrict__ vpwT, float* __restrict__ bias1d)
{
  int t = blockIdx.x * 256 + threadIdx.x;   // grid 64 -> 16384 threads
  for (int i = t; i < 65536; i += 16384){
    scw_bf[i] = f2bf(scw[i]);
    pjw_bf[i] = f2bf(pjw[i]);
  }
  { // vpwT[g][j][i] = vpw[g][i][j]
    int g = t >> 12, j = (t >> 6) & 63, i = t & 63;
    vpwT[t] = f2bf(vpw[g * 4096 + i * 64 + j]);
  }
  if (t < 4 * 511){ // bias depends only on (j-i): table per head
    int n = t / 511, ii = t - n * 511;
    float rel = (float)(ii - 255) * (8.0f / 255.0f);
    float sg = (rel > 0.f) ? 1.f : ((rel < 0.f) ? -1.f : 0.f);
    float feat = sg * log2f(fabsf(rel) + 1.0f) * (1.0f / 3.0f);
    float acc = 0.f;
    for (int h = 0; h < 64; h++){
      float hv = fmaxf(feat * w1[h] + b1[h], 0.f);
      acc += hv * w2[h * 4 + n];
    }
    bias1d[n * 511 + ii] = 1.0f / (1.0f + expf(-acc));
  }
}

// ---------------- K1: fused maxpool + depthwise3x3+ReLU + transpose to [pix][chan] bf16 ----
__global__ __launch_bounds__(256) void k1_dw(
    const float* __restrict__ x, const float* __restrict__ vdw, const float* __restrict__ vdwb,
    unsigned short* __restrict__ vdT, float* __restrict__ xp)
{
  __shared__ float wts[576];
  __shared__ float bl[64];
  __shared__ unsigned short vdt_t[64 * 66];
  int t = threadIdx.x;
  int bid = blockIdx.x;              // 8192 = 8 * 4 * 32 * 8
  int b = bid >> 10;
  int rem = bid & 1023;
  int c0 = (rem >> 8) * 64;
  int ty = (rem >> 3) & 31;
  int tx = rem & 7;
  int y0 = ty * 4, x0 = tx * 16;     // 4x16 pixel tile, 64 channels
  for (int i = t; i < 576; i += 256) wts[i] = vdw[c0 * 9 + i];
  if (t < 64) bl[t] = vdwb[c0 + t];
  __syncthreads();
  int wave = t >> 6, lane = t & 63;
  int py = lane >> 4, px = lane & 15;
  int y = y0 + py, xxp = x0 + px;
  for (int it = 0; it < 16; it++){
    int cl = it * 4 + wave;          // channel local 0..63 (wave-uniform)
    const float* xc = x + ((long)(b * C_ + c0 + cl)) * L_;
    float center = xc[y * W_ + xxp];
    float acc = bl[cl];
    #pragma unroll
    for (int dy = 0; dy < 3; dy++){
      int yy = y + dy - 1;
      if (yy < 0 || yy >= H_) continue;
      #pragma unroll
      for (int dx = 0; dx < 3; dx++){
        int xx2 = xxp + dx - 1;
        if (xx2 < 0 || xx2 >= W_) continue;
        acc += wts[cl * 9 + dy * 3 + dx] * xc[yy * W_ + xx2];
      }
    }
    float vd = fmaxf(acc, 0.f);
    vdt_t[lane * 66 + cl] = f2bf(vd);
    // 4x4 maxpool of x: reduce px within group-of-4 and all py
    float m = center;
    m = fmaxf(m, __shfl_xor(m, 1));
    m = fmaxf(m, __shfl_xor(m, 2));
    m = fmaxf(m, __shfl_xor(m, 16));
    m = fmaxf(m, __shfl_xor(m, 32));
    if (py == 0 && (px & 3) == 0){
      xp[((long)(b * C_ + c0 + cl)) * LP_ + ty * 32 + tx * 4 + (px >> 2)] = m;
    }
  }
  __syncthreads();
  #pragma unroll
  for (int r2 = 0; r2 < 2; r2++){
    int pix = (t >> 3) + 32 * r2;
    int slot = t & 7;
    long gp = (long)b * L_ + (long)(y0 + (pix >> 4)) * W_ + x0 + (pix & 15);
    const unsigned int* s1p = (const unsigned int*)(vdt_t + pix * 66 + slot * 8);
    uint4 v1; v1.x = s1p[0]; v1.y = s1p[1]; v1.z = s1p[2]; v1.w = s1p[3];
    *(uint4*)(vdT + gp * C_ + c0 + slot * 8) = v1;
  }
}

// ---------------- K2a: grouped 1x1 q,k on pooled input -> [b4n][c][d] f32 ----------------
__global__ __launch_bounds__(256) void k2a_qk(
    const float* __restrict__ xp, const float* __restrict__ qw, const float* __restrict__ qb,
    const float* __restrict__ kw, const float* __restrict__ kb,
    float* __restrict__ q_ws, float* __restrict__ k_ws)
{
  int bid = blockIdx.x;              // 128 = b*16 + g*4 + hd
  int b = bid >> 4, g = (bid >> 2) & 3, hd = bid & 3;
  int t = threadIdx.x;               // = d (0..255)
  float xr[64];
  const float* xpb = xp + ((long)(b * C_ + g * 64)) * LP_ + hd * 256 + t;
  #pragma unroll
  for (int j = 0; j < 64; j++) xr[j] = xpb[(long)j * LP_];
  const float* qwg = qw + g * 4096;
  const float* kwg = kw + g * 4096;
  long ob = ((long)((b * 4 + hd) * 256 + g * 64)) * 256 + t;
  for (int i = 0; i < 64; i++){
    float qa = qb[g * 64 + i];
    float ka = kb[g * 64 + i];
    #pragma unroll 16
    for (int j = 0; j < 64; j++){
      qa += qwg[i * 64 + j] * xr[j];
      ka += kwg[i * 64 + j] * xr[j];
    }
    q_ws[ob + (long)i * 256] = qa;
    k_ws[ob + (long)i * 256] = ka;
  }
}

// ---------------- K2b: row l2norm -> bf16 ----------------
__global__ __launch_bounds__(256) void k2b_norm(
    const float* __restrict__ q_ws, const float* __restrict__ k_ws,
    unsigned short* __restrict__ qn, unsigned short* __restrict__ kn)
{
  int wave = threadIdx.x >> 6, lane = threadIdx.x & 63;
  int row = blockIdx.x * 4 + wave;   // 16384 rows: first 8192 q, then k
  const float* src;
  unsigned short* dst;
  if (row < 8192){ src = q_ws + (long)row * 256; dst = qn + (long)row * 256; }
  else { src = k_ws + (long)(row - 8192) * 256; dst = kn + (long)(row - 8192) * 256; }
  float4 v = ((const float4*)src)[lane];
  float ss = v.x * v.x + v.y * v.y + v.z * v.z + v.w * v.w;
  ss += __shfl_xor(ss, 1); ss += __shfl_xor(ss, 2); ss += __shfl_xor(ss, 4);
  ss += __shfl_xor(ss, 8); ss += __shfl_xor(ss, 16); ss += __shfl_xor(ss, 32);
  float sc = 1.0f / fmaxf(sqrtf(ss), 1e-12f);
  unsigned int h0 = (unsigned int)f2bf(v.x * sc) | ((unsigned int)f2bf(v.y * sc) << 16);
  unsigned int h1 = (unsigned int)f2bf(v.z * sc) | ((unsigned int)f2bf(v.w * sc) << 16);
  uint2 pk; pk.x = h0; pk.y = h1;
  *(uint2*)(dst + lane * 4) = pk;
}

// ---------------- K3: sim = qn@kn^T (MFMA) + scale + bias + double softmax -> A bf16 ------
__global__ __launch_bounds__(256, 2) void k3_sim(
    const unsigned short* __restrict__ qn, const unsigned short* __restrict__ kn,
    const float* __restrict__ bias1d, const float* __restrict__ ls,
    const float* __restrict__ vpwb,
    unsigned short* __restrict__ A, float* __restrict__ s1)
{
  __shared__ unsigned short qt[64 * 256];  // [64 i][256 d] swizzled
  __shared__ unsigned short kt[256 * 64];  // [256 j][64 d] swizzled (per K-chunk)
  __shared__ float bias_l[512];
  __shared__ float vpwb_l[256];
  int t = threadIdx.x;
  int bid = blockIdx.x;                    // 128 = b4n*4 + itile
  int b4n = bid >> 2;
  int i0 = (bid & 3) * 64;
  int hd = b4n & 3;
  int wave = t >> 6, lane = t & 63;
  float scale = expf(fminf(ls[hd], logf(100.0f)));
  for (int i = t; i < 511; i += 256) bias_l[i] = bias1d[hd * 511 + i];
  if (t < 256) vpwb_l[t] = vpwb[t];
  const unsigned short* qsrc = qn + (long)b4n * 65536 + (long)i0 * 256;
  #pragma unroll
  for (int uu = 0; uu < 8; uu++){
    int idx = uu * 256 + t;
    int row = idx >> 5, slot = idx & 31;
    uint4 v = *(const uint4*)(qsrc + row * 256 + slot * 8);
    *(uint4*)(qt + row * 256 + (slot ^ (row & 7)) * 8) = v;
  }
  f32x4 acc[16];
  #pragma unroll
  for (int f = 0; f < 16; f++) acc[f] = (f32x4){0.f, 0.f, 0.f, 0.f};
  const unsigned short* ksrc = kn + (long)b4n * 65536;
  for (int kc = 0; kc < 4; kc++){
    __syncthreads();
    #pragma unroll
    for (int uu = 0; uu < 8; uu++){
      int idx = uu * 256 + t;
      int row = idx >> 3, slot = idx & 7;
      uint4 v = *(const uint4*)(ksrc + row * 256 + kc * 64 + slot * 8);
      *(uint4*)(kt + row * 64 + (slot ^ (row & 7)) * 8) = v;
    }
    __syncthreads();
    #pragma unroll
    for (int kg = 0; kg < 2; kg++){
      bf16x8 af = frag_ld(qt, wave * 16 + (lane & 15), kc * 8 + kg * 4 + (lane >> 4), 256);
      #pragma unroll
      for (int jt = 0; jt < 16; jt++){
        bf16x8 bfr = frag_ld(kt, jt * 16 + (lane & 15), kg * 4 + (lane >> 4), 64);
        acc[jt] = __builtin_amdgcn_mfma_f32_16x16x32_bf16(af, bfr, acc[jt], 0, 0, 0);
      }
    }
  }
  int g4 = lane >> 4, li = lane & 15;
  #pragma unroll
  for (int r = 0; r < 4; r++){
    int il = i0 + wave * 16 + g4 * 4 + r;   // head-local row
    float v[16], mx = -1e30f;
    #pragma unroll
    for (int f = 0; f < 16; f++){
      v[f] = acc[f][r] * scale + bias_l[f * 16 + li - il + 255];
      mx = fmaxf(mx, v[f]);
    }
    mx = fmaxf(mx, __shfl_xor(mx, 1));
    mx = fmaxf(mx, __shfl_xor(mx, 2));
    mx = fmaxf(mx, __shfl_xor(mx, 4));
    mx = fmaxf(mx, __shfl_xor(mx, 8));
    float s = 0.f;
    #pragma unroll
    for (int f = 0; f < 16; f++){ v[f] = __expf(v[f] - mx); s += v[f]; }
    s += __shfl_xor(s, 1); s += __shfl_xor(s, 2); s += __shfl_xor(s, 4); s += __shfl_xor(s, 8);
    float inv = 1.0f / s;
    float s2 = 0.f;
    #pragma unroll
    for (int f = 0; f < 16; f++){ v[f] = __expf(1.0f - v[f] * inv); s2 += v[f]; }
    s2 += __shfl_xor(s2, 1); s2 += __shfl_xor(s2, 2); s2 += __shfl_xor(s2, 4); s2 += __shfl_xor(s2, 8);
    float inv2 = 1.0f / s2;
    unsigned short* ap = A + (long)b4n * 65536 + (long)il * 256;
    float sd = 0.f;
    #pragma unroll
    for (int f = 0; f < 16; f++){
      float av = v[f] * inv2;
      ap[f * 16 + li] = f2bf(av);
      sd += av * vpwb_l[f * 16 + li];
    }
    sd += __shfl_xor(sd, 1); sd += __shfl_xor(sd, 2); sd += __shfl_xor(sd, 4); sd += __shfl_xor(sd, 8);
    if (li == 0) s1[b4n * 256 + il] = sd;   // (A @ v_pw_b)[c]
  }
}

// ---------------- K4a: T1t[b4n][col][c] = (A @ blockdiag(Vpw))^T, bf16 ----------------
__global__ __launch_bounds__(256, 2) void k4a_t1(
    const unsigned short* __restrict__ vpwT, const unsigned short* __restrict__ A,
    unsigned short* __restrict__ T1t)
{
  __shared__ unsigned short vt[64 * 64];
  __shared__ unsigned short at[256 * 64];
  int t = threadIdx.x;
  int b4n = blockIdx.x >> 2, g = blockIdx.x & 3;
  int wave = t >> 6, lane = t & 63;
  #pragma unroll
  for (int uu = 0; uu < 2; uu++){
    int idx = uu * 256 + t;
    int row = idx >> 3, slot = idx & 7;
    uint4 v = *(const uint4*)(vpwT + (g * 64 + row) * 64 + slot * 8);
    *(uint4*)(vt + row * 64 + (slot ^ (row & 7)) * 8) = v;
  }
  #pragma unroll
  for (int uu = 0; uu < 8; uu++){
    int idx = uu * 256 + t;
    int row = idx >> 3, slot = idx & 7;
    uint4 v = *(const uint4*)(A + (long)b4n * 65536 + row * 256 + g * 64 + slot * 8);
    *(uint4*)(at + row * 64 + (slot ^ (row & 7)) * 8) = v;
  }
  __syncthreads();
  f32x4 acc[16];
  #pragma unroll
  for (int f = 0; f < 16; f++) acc[f] = (f32x4){0.f, 0.f, 0.f, 0.f};
  #pragma unroll
  for (int kg = 0; kg < 2; kg++){
    bf16x8 af = frag_ld(vt, wave * 16 + (lane & 15), kg * 4 + (lane >> 4), 64);
    #pragma unroll
    for (int nt = 0; nt < 16; nt++){
      bf16x8 bfr = frag_ld(at, nt * 16 + (lane & 15), kg * 4 + (lane >> 4), 64);
      acc[nt] = __builtin_amdgcn_mfma_f32_16x16x32_bf16(af, bfr, acc[nt], 0, 0, 0);
    }
  }
  int col = g * 64 + wave * 16 + (lane >> 4) * 4;
  #pragma unroll
  for (int nt = 0; nt < 16; nt++){
    #pragma unroll
    for (int r = 0; r < 4; r++){
      T1t[(long)b4n * 65536 + (long)(col + r) * 256 + nt * 16 + (lane & 15)] = f2bf(acc[nt][r]);
    }
  }
}

// ---------------- Kvb2: vb[b4n][o] = proj_w @ (A @ v_pw_b) ----------------
__global__ __launch_bounds__(256) void kvb2(
    const float* __restrict__ pjw, const float* __restrict__ s1, float* __restrict__ vb)
{
  int wave = threadIdx.x >> 6, lane = threadIdx.x & 63;
  int row = blockIdx.x * 4 + wave;    // 8192 rows
  int bn = row >> 8, o = row & 255;
  float4 w = ((const float4*)(pjw + (long)o * 256))[lane];
  float4 s = ((const float4*)(s1 + (long)bn * 256))[lane];
  float d = w.x * s.x + w.y * s.y + w.z * s.z + w.w * s.w;
  d += __shfl_xor(d, 1); d += __shfl_xor(d, 2); d += __shfl_xor(d, 4);
  d += __shfl_xor(d, 8); d += __shfl_xor(d, 16); d += __shfl_xor(d, 32);
  if (lane == 0) vb[row] = d;
}

// ---------------- K4b: W1[b4n][o][col] = proj_w @ T1 ----------------
__global__ __launch_bounds__(256, 2) void k4b_w1(
    const unsigned short* __restrict__ pjw_bf, const unsigned short* __restrict__ T1t,
    unsigned short* __restrict__ W1)
{
  __shared__ unsigned short at[128 * 64];
  __shared__ unsigned short bt[128 * 64];
  int t = threadIdx.x;
  int b4n = blockIdx.x >> 2;
  int m0 = ((blockIdx.x >> 1) & 1) * 128;
  int n0 = (blockIdx.x & 1) * 128;
  int wave = t >> 6, lane = t & 63;
  int wr = wave >> 1, wc = wave & 1;
  f32x4 acc[4][4];
  #pragma unroll
  for (int mi = 0; mi < 4; mi++)
    #pragma unroll
    for (int ni = 0; ni < 4; ni++) acc[mi][ni] = (f32x4){0.f, 0.f, 0.f, 0.f};
  for (int kc = 0; kc < 4; kc++){
    __syncthreads();
    #pragma unroll
    for (int uu = 0; uu < 4; uu++){
      int idx = uu * 256 + t;
      int row = idx >> 3, slot = idx & 7;
      int dof = row * 64 + (slot ^ (row & 7)) * 8;
      *(uint4*)(at + dof) = *(const uint4*)(pjw_bf + (long)(m0 + row) * 256 + kc * 64 + slot * 8);
      *(uint4*)(bt + dof) = *(const uint4*)(T1t + (long)b4n * 65536 + (long)(n0 + row) * 256 + kc * 64 + slot * 8);
    }
    __syncthreads();
    #pragma unroll
    for (int kg = 0; kg < 2; kg++){
      bf16x8 a[4], bb[4];
      #pragma unroll
      for (int mi = 0; mi < 4; mi++) a[mi] = frag_ld(at, wr * 64 + mi * 16 + (lane & 15), kg * 4 + (lane >> 4), 64);
      #pragma unroll
      for (int ni = 0; ni < 4; ni++) bb[ni] = frag_ld(bt, wc * 64 + ni * 16 + (lane & 15), kg * 4 + (lane >> 4), 64);
      #pragma unroll
      for (int mi = 0; mi < 4; mi++)
        #pragma unroll
        for (int ni = 0; ni < 4; ni++)
          acc[mi][ni] = __builtin_amdgcn_mfma_f32_16x16x32_bf16(a[mi], bb[ni], acc[mi][ni], 0, 0, 0);
    }
  }
  #pragma unroll
  for (int mi = 0; mi < 4; mi++){
    int o = m0 + wr * 64 + mi * 16 + (lane >> 4) * 4;
    #pragma unroll
    for (int ni = 0; ni < 4; ni++){
      int col = n0 + wc * 64 + ni * 16 + (lane & 15);
      #pragma unroll
      for (int r = 0; r < 4; r++)
        W1[(long)b4n * 65536 + (long)(o + r) * 256 + col] = f2bf(acc[mi][ni][r]);
    }
  }
}

// ---------------- K5: dual GEMM (W1@vd ; sc_w@x) + GELU/BN + ReLU shortcut + add ----------
// grid (128, 8): ptile = blockIdx.x (128 pixels = one image row), b = blockIdx.y.
// Inner loop over m0 {0,128} so vdT/x B-tiles are fetched once (2nd pass L2-hits).
__global__ __launch_bounds__(256, 2) void k5_final(
    const unsigned short* __restrict__ W1, const unsigned short* __restrict__ scw_bf,
    const unsigned short* __restrict__ vdT, const float* __restrict__ x,
    const float* __restrict__ pjb, const float* __restrict__ vb,
    const float* __restrict__ scb, const float* __restrict__ gamma, const float* __restrict__ beta,
    float* __restrict__ out)
{
  __shared__ unsigned short a1t[128 * 64];
  __shared__ unsigned short a2t[128 * 64];
  __shared__ unsigned short b1t[128 * 64];
  __shared__ unsigned short b2t[128 * 64];
  __shared__ float ep[1024];
  int t = threadIdx.x;
  int ptile = blockIdx.x;            // 128 pixel-tiles per image (one row each)
  int b = blockIdx.y;
  int hd = ptile >> 5;               // head = pixel/4096
  int l0 = ptile * 128;
  int b4n = b * 4 + hd;
  int wave = t >> 6, lane = t & 63;
  int wr = wave >> 1, wc = wave & 1;
  // epilogue params for all 256 output channels
  if (t < 256){
    ep[t]       = pjb[t] + vb[b4n * 256 + t];
    ep[256 + t] = gamma[t] * rsqrtf(1.00001f);
    ep[512 + t] = beta[t];
    ep[768 + t] = scb[t];
  }
  const unsigned short* b1s = vdT + ((long)b * L_ + l0) * 256;
  const float* xs = x + (long)b * C_ * L_ + l0;

  for (int m0 = 0; m0 < 256; m0 += 128){
    f32x4 acc1[4][4], acc2[4][4];
    #pragma unroll
    for (int mi = 0; mi < 4; mi++)
      #pragma unroll
      for (int ni = 0; ni < 4; ni++){
        acc1[mi][ni] = (f32x4){0.f, 0.f, 0.f, 0.f};
        acc2[mi][ni] = (f32x4){0.f, 0.f, 0.f, 0.f};
      }
    const unsigned short* a1s = W1 + (long)b4n * 65536 + (long)m0 * 256;
    const unsigned short* a2s = scw_bf + (long)m0 * 256;
    for (int kc = 0; kc < 4; kc++){
      __syncthreads();
      int ko = kc * 64;
      #pragma unroll
      for (int uu = 0; uu < 4; uu++){
        int idx = uu * 256 + t;
        int row = idx >> 3, slot = idx & 7;
        long so = (long)row * 256 + ko + slot * 8;
        int dof = row * 64 + (slot ^ (row & 7)) * 8;
        *(uint4*)(a1t + dof) = *(const uint4*)(a1s + so);
        *(uint4*)(a2t + dof) = *(const uint4*)(a2s + so);
        *(uint4*)(b1t + dof) = *(const uint4*)(b1s + so);
      }
      // b2t: transpose-stage x (f32 [ch][pix] -> bf16 [pix][ch] swizzled)
      const float* xsrc = xs + (long)ko * L_;
      #pragma unroll
      for (int uu = 0; uu < 2; uu++){
        int idx = uu * 256 + t;
        int cq = idx >> 5;           // channel quad 0..15 -> cl = cq*4
        int p4 = idx & 31;
        const float* xc = xsrc + (long)(cq * 4) * L_;
        int cl = cq * 4;
        #pragma unroll
        for (int j = 0; j < 4; j++){
          int pix = p4 + j * 32;
          unsigned int h0 = f2bf(xc[pix]);
          unsigned int h1 = f2bf(xc[pix + L_]);
          unsigned int h2 = f2bf(xc[pix + 2 * L_]);
          unsigned int h3 = f2bf(xc[pix + 3 * L_]);
          uint2 pk; pk.x = h0 | (h1 << 16); pk.y = h2 | (h3 << 16);
          *(uint2*)(b2t + pix * 64 + (((cl >> 3) ^ (pix & 7)) << 3) + (cl & 7)) = pk;
        }
      }
      __syncthreads();
      #pragma unroll
      for (int kg = 0; kg < 2; kg++){
        bf16x8 a1[4], a2[4], b1[4], b2[4];
        #pragma unroll
        for (int mi = 0; mi < 4; mi++){
          int ro = wr * 64 + mi * 16 + (lane & 15);
          int sl = kg * 4 + (lane >> 4);
          a1[mi] = frag_ld(a1t, ro, sl, 64);
          a2[mi] = frag_ld(a2t, ro, sl, 64);
        }
        #pragma unroll
        for (int ni = 0; ni < 4; ni++){
          int ro = wc * 64 + ni * 16 + (lane & 15);
          int sl = kg * 4 + (lane >> 4);
          b1[ni] = frag_ld(b1t, ro, sl, 64);
          b2[ni] = frag_ld(b2t, ro, sl, 64);
        }
        #pragma unroll
        for (int mi = 0; mi < 4; mi++)
          #pragma unroll
          for (int ni = 0; ni < 4; ni++){
            acc1[mi][ni] = __builtin_amdgcn_mfma_f32_16x16x32_bf16(a1[mi], b1[ni], acc1[mi][ni], 0, 0, 0);
            acc2[mi][ni] = __builtin_amdgcn_mfma_f32_16x16x32_bf16(a2[mi], b2[ni], acc2[mi][ni], 0, 0, 0);
          }
      }
    }
    #pragma unroll
    for (int mi = 0; mi < 4; mi++){
      int olb = wr * 64 + mi * 16 + (lane >> 4) * 4;
      #pragma unroll
      for (int ni = 0; ni < 4; ni++){
        int col = wc * 64 + ni * 16 + (lane & 15);
        #pragma unroll
        for (int r = 0; r < 4; r++){
          int ol = olb + r;
          int o = m0 + ol;
          float z = acc1[mi][ni][r] + ep[o];
          float yv = z * 0.5f * (1.0f + erff(z * 0.70710678118654752f));
          yv = yv * ep[256 + o] + ep[512 + o];
          float sv = fmaxf(acc2[mi][ni][r] + ep[768 + o], 0.f);
          out[((long)(b * C_ + o)) * L_ + l0 + col] = yv + sv;
        }
      }
    }
  }
}

extern "C" void kernel_launch(void* const* d_in, const int* in_sizes, int n_in,
                              void* d_out, int out_size, void* d_ws, size_t ws_size,
                              hipStream_t stream)
{
  (void)in_sizes; (void)n_in; (void)out_size; (void)ws_size;
  const float* x        = (const float*)d_in[0];
  const float* sc_w     = (const float*)d_in[1];
  const float* sc_b     = (const float*)d_in[2];
  const float* q_w      = (const float*)d_in[3];
  const float* q_b      = (const float*)d_in[4];
  const float* k_w      = (const float*)d_in[5];
  const float* k_b      = (const float*)d_in[6];
  const float* v_dw_w   = (const float*)d_in[7];
  const float* v_dw_b   = (const float*)d_in[8];
  const float* v_pw_w   = (const float*)d_in[9];
  const float* v_pw_b   = (const float*)d_in[10];
  const float* logit_sc = (const float*)d_in[11];
  const float* cpb_w1   = (const float*)d_in[12];
  const float* cpb_b1   = (const float*)d_in[13];
  const float* cpb_w2   = (const float*)d_in[14];
  const float* proj_w   = (const float*)d_in[15];
  const float* proj_b   = (const float*)d_in[16];
  const float* bn_gamma = (const float*)d_in[17];
  const float* bn_beta  = (const float*)d_in[18];
  float* out = (float*)d_out;

  // ---- workspace arena: 88.4 MB total, lifetime-aliased (ws_size safety) ----
  char* ws = (char*)d_ws;
  const size_t MB = 1048576;
  unsigned short* vdT    = (unsigned short*)(ws + 0);         // [0,64MB) persistent to k5
  float* xp              = (float*)(ws + 64 * MB);            // [64,72) k1->k2a
  float* q_ws            = (float*)(ws + 72 * MB);            // [72,80) k2a->k2b
  float* k_ws            = (float*)(ws + 80 * MB);            // [80,88) k2a->k2b
  unsigned short* qn     = (unsigned short*)(ws + 64 * MB);   // [64,68) k2b->k3 (over dead xp)
  unsigned short* kn     = (unsigned short*)(ws + 68 * MB);   // [68,72) k2b->k3 (over dead xp)
  unsigned short* A      = (unsigned short*)(ws + 72 * MB);   // [72,76) k3->k4a (over dead q_ws)
  unsigned short* T1t    = (unsigned short*)(ws + 76 * MB);   // [76,80) k4a->k4b (over dead q_ws)
  unsigned short* W1     = (unsigned short*)(ws + 80 * MB);   // [80,84) k4b->k5 (over dead k_ws)
  unsigned short* scw_bf = (unsigned short*)(ws + 88 * MB);               // 128KB
  unsigned short* pjw_bf = (unsigned short*)(ws + 88 * MB + 131072);      // 128KB
  unsigned short* vpwT   = (unsigned short*)(ws + 88 * MB + 262144);      // 32KB
  float* bias1d          = (float*)(ws + 88 * MB + 294912);               // 8KB
  float* s1              = (float*)(ws + 88 * MB + 303104);               // 32KB
  float* vb              = (float*)(ws + 88 * MB + 335872);               // 32KB -> ends 88MB+368KB

  hipLaunchKernelGGL(k0_prep, dim3(64), dim3(256), 0, stream,
                     sc_w, proj_w, v_pw_w, cpb_w1, cpb_b1, cpb_w2,
                     scw_bf, pjw_bf, vpwT, bias1d);
  hipLaunchKernelGGL(k1_dw, dim3(8192), dim3(256), 0, stream,
                     x, v_dw_w, v_dw_b, vdT, xp);
  hipLaunchKernelGGL(k2a_qk, dim3(128), dim3(256), 0, stream,
                     xp, q_w, q_b, k_w, k_b, q_ws, k_ws);
  hipLaunchKernelGGL(k2b_norm, dim3(4096), dim3(256), 0, stream,
                     q_ws, k_ws, qn, kn);
  hipLaunchKernelGGL(k3_sim, dim3(128), dim3(256), 0, stream,
                     qn, kn, bias1d, logit_sc, v_pw_b, A, s1);
  hipLaunchKernelGGL(k4a_t1, dim3(128), dim3(256), 0, stream,
                     vpwT, A, T1t);
  hipLaunchKernelGGL(kvb2, dim3(2048), dim3(256), 0, stream,
                     proj_w, s1, vb);
  hipLaunchKernelGGL(k4b_w1, dim3(128), dim3(256), 0, stream,
                     pjw_bf, T1t, W1);
  hipLaunchKernelGGL(k5_final, dim3(128, 8), dim3(256), 0, stream,
                     W1, scw_bf, vdT, x, proj_b, vb, sc_b, bn_gamma, bn_beta, out);
}